// Round 5
// baseline (122.418 us; speedup 1.0000x reference)
//
#include <hip/hip_runtime.h>
#include <cmath>

// Problem constants: F=2048, HOP=N=1024, B=8, T=2^20
#define BATCH   8
#define TLEN    1048576
#define NFRM    1025                 // frames per batch row
#define MROWS   (BATCH * NFRM)       // 8200 GEMM rows
#define MPAD    8256                 // 129 * 64 (64-row m-tiles)
#define NDIM    1024
#define KDIM    1024

typedef __attribute__((ext_vector_type(8))) _Float16 half8;
typedef __attribute__((ext_vector_type(4))) float    f32x4;

__device__ __forceinline__ unsigned short f2h(float f) {
    union { _Float16 h; unsigned short s; } v;
    v.h = (_Float16)f;
    return v.s;
}

// async global->LDS, 16B per lane; LDS dest = wave-uniform base + lane*16
__device__ __forceinline__ void gl_lds16(const void* g, void* l) {
    __builtin_amdgcn_global_load_lds(
        (const __attribute__((address_space(1))) void*)(unsigned long long)(uintptr_t)g,
        (__attribute__((address_space(3))) void*)(unsigned int)(uintptr_t)l,
        16, 0, 0);
}

// ---------------------------------------------------------------------------
// Kernel 1 (fused prep): blocks [0,1024) generate the scaled DCT-IV matrix
// C4[p][k] = cos(pi*(2p+1)(2k+1)/4096) * sqrt(2/1024) in fp16 (4 vals/thread);
// blocks [1024, 1024+MPAD) do the MDCT fold for row r = blockIdx.x - 1024.
//
// Fold: y[n] = w[n]*x[off+n], off=(t-1)*1024:
//   p in [0,512):    u[p] = -( y[1535-p] + y[1536+p] )   (zero iff t==1024)
//   p in [512,1024): u[p] =    y[p-512]  - y[1535-p]     (zero iff t==0)
// ---------------------------------------------------------------------------
__global__ __launch_bounds__(256) void prep_kernel(const float* __restrict__ x,
                                                   const float* __restrict__ w,
                                                   ushort4* __restrict__ u,
                                                   ushort4* __restrict__ c4) {
    const int blk = blockIdx.x;
    const int tid = threadIdx.x;
    if (blk < 1024) {
        int idx  = blk * 256 + tid;
        int base = idx * 4;
        int p = base >> 10;
        int k = base & 1023;
        int a = 2 * p + 1;
        int m0 = a * (2 * k + 1);
        ushort4 v;
        v.x = f2h(cospif((float)((m0        ) & 8191) * (1.0f / 4096.0f)) * 0.04419417382415922f);
        v.y = f2h(cospif((float)((m0 + 2 * a) & 8191) * (1.0f / 4096.0f)) * 0.04419417382415922f);
        v.z = f2h(cospif((float)((m0 + 4 * a) & 8191) * (1.0f / 4096.0f)) * 0.04419417382415922f);
        v.w = f2h(cospif((float)((m0 + 6 * a) & 8191) * (1.0f / 4096.0f)) * 0.04419417382415922f);
        c4[idx] = v;
        return;
    }
    const int r = blk - 1024;
    const int p = tid * 4;
    ushort4 val = {0, 0, 0, 0};
    if (r < MROWS) {
        const int b = r / NFRM;
        const int t = r - b * NFRM;
        const float* xb = x + b * TLEN + (t - 1) * 1024;
        const bool low = (p < 512);
        const bool valid = low ? (t != NFRM - 1) : (t != 0);
        if (valid) {
            float4 xr, wr, xf, wf, res;
            const int rb = 1532 - p;                  // reversed base
            const int fb = low ? (1536 + p) : (p - 512);
            xr = *(const float4*)(xb + rb);
            wr = *(const float4*)(w  + rb);
            xf = *(const float4*)(xb + fb);
            wf = *(const float4*)(w  + fb);
            if (low) {
                res.x = -(wr.w * xr.w + wf.x * xf.x);
                res.y = -(wr.z * xr.z + wf.y * xf.y);
                res.z = -(wr.y * xr.y + wf.z * xf.z);
                res.w = -(wr.x * xr.x + wf.w * xf.w);
            } else {
                res.x = wf.x * xf.x - wr.w * xr.w;
                res.y = wf.y * xf.y - wr.z * xr.z;
                res.z = wf.z * xf.z - wr.y * xr.y;
                res.w = wf.w * xf.w - wr.x * xr.x;
            }
            val.x = f2h(res.x); val.y = f2h(res.y);
            val.z = f2h(res.z); val.w = f2h(res.w);
        }
    }
    u[r * 256 + tid] = val;
}

// ---------------------------------------------------------------------------
// Kernel 2: out[8200 x 1024] = u[8256 x 1024] @ C4[1024 x 1024], f16 MFMA.
// 64x128 block tile (M=64, N=128), 4 waves each computing 32x64 (acc 2x4).
// BK=64 as two BK=32 sub-tiles, global_load_lds width-16 staging, 64-B
// unpadded LDS rows.  Grid = 129 m-tiles x 8 n-tiles = 1032 blocks ->
// 4 blocks/CU, 16 waves/CU (50% occupancy) — R4 post-mortem showed the
// 128x128 version was latency-bound at 8 waves/CU (Occ 15%, MfmaUtil 14.5%).
// Fragment layouts: A/B: m|n = lane&15, k = (lane>>4)*8 + j;
// C: col = lane&15, row = (lane>>4)*4 + reg.
// ---------------------------------------------------------------------------
__global__ __launch_bounds__(256, 4)
void mdct_gemm(const unsigned short* __restrict__ u,
               const unsigned short* __restrict__ c4,
               float* __restrict__ out) {
    __shared__ unsigned short As[2][64 * 32];    // 2 x 4 KB
    __shared__ unsigned short Bs[2][128 * 32];   // 2 x 8 KB

    const int m0 = blockIdx.x * 64;              // m fastest (XCD dup heuristic)
    const int n0 = blockIdx.y * 128;
    const int tid  = threadIdx.x;
    const int lane = tid & 63;
    const int wv   = tid >> 6;
    const int wm   = wv & 1;                     // wave m-half (32 rows)
    const int wn   = wv >> 1;                    // wave n-half (64 cols)
    const int m16  = lane & 15;
    const int quad = lane >> 4;

    f32x4 acc[2][4] = {};

    // staging: lane L of wave wv covers
    //   A: row wv*16 + L/4, 16B chunk L%4          (16 rows/wave)
    //   B: rows wv*32 + L/4 and wv*32+16+L/4       (32 rows/wave, 2 chunks)
    const int lrow = lane >> 2;
    const int lcol = lane & 3;
    const unsigned short* gA = u  + (m0 + wv * 16 + lrow) * KDIM + lcol * 8;
    const unsigned short* gB = c4 + (n0 + wv * 32 + lrow) * KDIM + lcol * 8;
    unsigned short* lA0 = &As[0][wv * 512];
    unsigned short* lA1 = &As[1][wv * 512];
    unsigned short* lB0 = &Bs[0][wv * 1024];
    unsigned short* lB1 = &Bs[1][wv * 1024];

    for (int k0 = 0; k0 < KDIM; k0 += 64) {
        __syncthreads();
        gl_lds16(gA + k0,                  lA0);
        gl_lds16(gA + k0 + 32,             lA1);
        gl_lds16(gB + k0,                  lB0);
        gl_lds16(gB + k0      + 16 * KDIM, lB0 + 512);
        gl_lds16(gB + k0 + 32,             lB1);
        gl_lds16(gB + k0 + 32 + 16 * KDIM, lB1 + 512);
        __syncthreads();

#pragma unroll
        for (int h = 0; h < 2; ++h) {
            half8 af[2], bf[4];
#pragma unroll
            for (int i = 0; i < 2; ++i)
                af[i] = *(const half8*)&As[h][(wm * 32 + i * 16 + m16) * 32 + quad * 8];
#pragma unroll
            for (int i = 0; i < 4; ++i)
                bf[i] = *(const half8*)&Bs[h][(wn * 64 + i * 16 + m16) * 32 + quad * 8];
#pragma unroll
            for (int mi = 0; mi < 2; ++mi)
#pragma unroll
                for (int ni = 0; ni < 4; ++ni)
                    acc[mi][ni] = __builtin_amdgcn_mfma_f32_16x16x32_f16(
                        af[mi], bf[ni], acc[mi][ni], 0, 0, 0);
        }
    }

    const int colb = n0 + wn * 64 + m16;
    const int rowb = m0 + wm * 32 + quad * 4;
    const bool full = (m0 + 64 <= MROWS);
#pragma unroll
    for (int mi = 0; mi < 2; ++mi) {
#pragma unroll
        for (int ni = 0; ni < 4; ++ni) {
#pragma unroll
            for (int j = 0; j < 4; ++j) {
                int r = rowb + mi * 16 + j;
                if (full || r < MROWS)
                    out[r * NDIM + colb + ni * 16] = acc[mi][ni][j];
            }
        }
    }
}

// ---------------------------------------------------------------------------
extern "C" void kernel_launch(void* const* d_in, const int* in_sizes, int n_in,
                              void* d_out, int out_size, void* d_ws, size_t ws_size,
                              hipStream_t stream) {
    const float* x = (const float*)d_in[0];   // (8, 1048576) fp32
    const float* w = (const float*)d_in[1];   // (2048,) fp32
    float* out = (float*)d_out;               // (8, 1025, 1024) fp32

    unsigned short* c4 = (unsigned short*)d_ws;          // 1024*1024 f16 (2 MB)
    unsigned short* u  = c4 + 1024 * 1024;               // 8256*1024 f16 (17 MB)

    prep_kernel<<<1024 + MPAD, 256, 0, stream>>>(x, w, (ushort4*)u, (ushort4*)c4);
    dim3 grid(MPAD / 64, NDIM / 128);                    // 129 x 8 = 1032 blocks
    mdct_gemm<<<grid, 256, 0, stream>>>(u, c4, out);
}

// Round 6
// 97.402 us; speedup vs baseline: 1.2568x; 1.2568x over previous
//
#include <hip/hip_runtime.h>
#include <cmath>

// Problem constants: F=2048, HOP=N=1024, B=8, T=2^20
#define BATCH   8
#define TLEN    1048576
#define NFRM    1025                 // frames per batch row
#define MROWS   (BATCH * NFRM)       // 8200 frames total

// ---------------------------------------------------------------------------
// Fully-fused MDCT: one block per frame.
//   1. fold x (windowed) -> u[1024] fp32 in LDS      (same fold as R1-R5,
//      which validated against the reference through the GEMM path)
//   2. DCT-IV(u) via 512-pt complex FFT:
//        z[n] = (u[2n] + i*u[1023-2n]) * cis(-pi*(4n+1)/4096)
//        Z = FFT_512(z)              (Stockham autosort, natural order out)
//        A[k] = Z[k] * cis(-pi*(4k+1)/4096)
//        out[2k] = Re(A[k])*s, out[1023-2k] = -Im(A[k])*s, s = sqrt(2/1024)
//      (identity hand-verified at N=4 against the DFT)
//   3. stage results in LDS, coalesced float4 store.
// Replaces prep + 17-GFLOP GEMM (stuck latency-bound at ~42 us across 4
// structural variants) with ~0.25 GFLOP of memory-bound work.
// LDS = 4 KB fold + 2 x 4 KB FFT ping-pong = 12.25 KB -> 8 blocks/CU.
// Stockham reads are stride-1 by construction (q + s*p == tid).
// ---------------------------------------------------------------------------
__global__ __launch_bounds__(256)
void mdct_fft_kernel(const float* __restrict__ x,
                     const float* __restrict__ w,
                     float* __restrict__ out)
{
    __shared__ float  uf[1024];
    __shared__ float2 za[512];
    __shared__ float2 zb[512];

    const int r   = blockIdx.x;
    const int tid = threadIdx.x;
    const int b = r / NFRM;
    const int t = r - b * NFRM;

    // ---- fold: y[n] = w[n]*x[(t-1)*1024 + n];
    //   p in [0,512):    u[p] = -( y[1535-p] + y[1536+p] )   (zero iff t==1024)
    //   p in [512,1024): u[p] =    y[p-512]  - y[1535-p]     (zero iff t==0)
    // Interior loads always in-bounds; edge frames zero exactly one half.
    {
        const int p = tid * 4;
        const float* xb = x + b * TLEN + (t - 1) * 1024;
        const bool low = (p < 512);
        const bool valid = low ? (t != NFRM - 1) : (t != 0);
        float4 res = {0.0f, 0.0f, 0.0f, 0.0f};
        if (valid) {
            const int rb = 1532 - p;                  // reversed base
            const int fb = low ? (1536 + p) : (p - 512);
            float4 xr = *(const float4*)(xb + rb);
            float4 wr = *(const float4*)(w  + rb);
            float4 xf = *(const float4*)(xb + fb);
            float4 wf = *(const float4*)(w  + fb);
            if (low) {
                res.x = -(wr.w * xr.w + wf.x * xf.x);
                res.y = -(wr.z * xr.z + wf.y * xf.y);
                res.z = -(wr.y * xr.y + wf.z * xf.z);
                res.w = -(wr.x * xr.x + wf.w * xf.w);
            } else {
                res.x = wf.x * xf.x - wr.w * xr.w;
                res.y = wf.y * xf.y - wr.z * xr.z;
                res.z = wf.z * xf.z - wr.y * xr.y;
                res.w = wf.w * xf.w - wr.x * xr.x;
            }
        }
        *(float4*)&uf[p] = res;
    }
    __syncthreads();

    // ---- pre-twiddle: z[n] = (u[2n] + i*u[1023-2n]) * (c - i*s) ----
#pragma unroll
    for (int h = 0; h < 2; ++h) {
        int n = tid + h * 256;
        float re = uf[2 * n];
        float im = uf[1023 - 2 * n];
        float a = (float)(4 * n + 1) * (1.0f / 4096.0f);
        float c = cospif(a), s = sinpif(a);
        za[n] = make_float2(re * c + im * s, im * c - re * s);
    }

    // ---- 512-pt Stockham radix-2 FFT (9 stages, autosort) ----
    // invariant: s * mh == 256; reads X[tid], X[tid+256]; twiddle e^{-i*pi*p/mh}
    float2* X = za;
    float2* Y = zb;
    int mh = 256;
    int ls = 0;
#pragma unroll
    for (int st = 0; st < 9; ++st) {
        __syncthreads();
        const int s = 1 << ls;
        const int p = tid >> ls;
        float ang = (float)p * (1.0f / (float)mh);   // in pi units
        float c = cospif(ang), sn = sinpif(ang);     // wp = c - i*sn
        float2 a  = X[tid];
        float2 bv = X[tid + 256];
        float2 sum = make_float2(a.x + bv.x, a.y + bv.y);
        float dx = a.x - bv.x, dy = a.y - bv.y;
        float2 wd = make_float2(dx * c + dy * sn, dy * c - dx * sn);
        Y[tid + s * p]     = sum;    // q + s*(2p)   == tid + s*p
        Y[tid + s * p + s] = wd;     // q + s*(2p+1)
        float2* tmp = X; X = Y; Y = tmp;
        mh >>= 1; ++ls;
    }
    __syncthreads();

    // ---- post-twiddle + DCT-IV output ordering (staged into uf) ----
#pragma unroll
    for (int h = 0; h < 2; ++h) {
        int k = tid + h * 256;
        float2 Zk = X[k];
        float a = (float)(4 * k + 1) * (1.0f / 4096.0f);
        float c = cospif(a), s = sinpif(a);
        float re = Zk.x * c + Zk.y * s;              // Re(Z * (c - i*s))
        float im = Zk.y * c - Zk.x * s;              // Im(Z * (c - i*s))
        uf[2 * k]        =  re * 0.04419417382415922f;   // sqrt(2/1024)
        uf[1023 - 2 * k] = -im * 0.04419417382415922f;
    }
    __syncthreads();

    // ---- coalesced store ----
    *(float4*)&out[r * 1024 + tid * 4] = *(const float4*)&uf[tid * 4];
}

// ---------------------------------------------------------------------------
extern "C" void kernel_launch(void* const* d_in, const int* in_sizes, int n_in,
                              void* d_out, int out_size, void* d_ws, size_t ws_size,
                              hipStream_t stream) {
    const float* x = (const float*)d_in[0];   // (8, 1048576) fp32
    const float* w = (const float*)d_in[1];   // (2048,) fp32
    float* out = (float*)d_out;               // (8, 1025, 1024) fp32
    (void)d_ws; (void)ws_size;

    mdct_fft_kernel<<<MROWS, 256, 0, stream>>>(x, w, out);
}

// Round 7
// 92.977 us; speedup vs baseline: 1.3166x; 1.0476x over previous
//
#include <hip/hip_runtime.h>
#include <cmath>

// Problem constants: F=2048, HOP=N=1024, B=8, T=2^20
#define BATCH   8
#define TLEN    1048576
#define NFRM    1025                 // frames per batch row
#define MROWS   (BATCH * NFRM)       // 8200 frames total

// XOR swizzle for the FFT ping-pong buffers: breaks the power-of-2 write
// strides of Stockham passes (pass0/1 writes were 16-way conflicted raw;
// with swizzle every pass's read AND write pattern is 4 lanes/bank-pair =
// conflict-free).  phi is a bijection on [0,512) (xor of high bits into low).
#define SWZ(i) ((i) ^ (((i) >> 4) & 15))

// ---------------------------------------------------------------------------
// Fully-fused MDCT: one block per frame.
//   1. fold x (windowed) -> u[1024] fp32 in LDS   (same fold as R1-R6)
//   2. DCT-IV(u) via 512-pt complex FFT:
//        z[n] = (u[2n] + i*u[1023-2n]) * cis(-pi*(4n+1)/4096)
//        Z = FFT_512(z)            (Stockham autosort, natural-order out)
//        A[k] = Z[k] * cis(-pi*(4k+1)/4096)
//        out[2k] = Re(A)*s, out[1023-2k] = -Im(A)*s, s = sqrt(2/1024)
//   FFT = 4 radix-4 Stockham passes (each = two fused radix-2 stages,
//   composition verified against the R6 radix-2 network) + final radix-2
//   kept in registers and fused with the post-twiddle.
//   LDS round-trips 9 -> 4, syncthreads 11 -> 7, stage trig 9 pairs -> 4
//   pairs + register angle-addition for w2 = w1^2, w3 = w1*w2.
// LDS = 4 KB fold + 2 x 4 KB ping-pong = 12.25 KB -> 8 blocks/CU (32 waves).
// ---------------------------------------------------------------------------
__global__ __launch_bounds__(256)
void mdct_fft_kernel(const float* __restrict__ x,
                     const float* __restrict__ w,
                     float* __restrict__ out)
{
    __shared__ float  uf[1024];
    __shared__ float2 za[512];
    __shared__ float2 zb[512];

    const int r   = blockIdx.x;
    const int tid = threadIdx.x;
    const int b = r / NFRM;
    const int t = r - b * NFRM;

    // ---- fold: y[n] = w[n]*x[(t-1)*1024 + n];
    //   p in [0,512):    u[p] = -( y[1535-p] + y[1536+p] )   (zero iff t==1024)
    //   p in [512,1024): u[p] =    y[p-512]  - y[1535-p]     (zero iff t==0)
    {
        const int p = tid * 4;
        const float* xb = x + b * TLEN + (t - 1) * 1024;
        const bool low = (p < 512);
        const bool valid = low ? (t != NFRM - 1) : (t != 0);
        float4 res = {0.0f, 0.0f, 0.0f, 0.0f};
        if (valid) {
            const int rb = 1532 - p;                  // reversed base
            const int fb = low ? (1536 + p) : (p - 512);
            float4 xr = *(const float4*)(xb + rb);
            float4 wr = *(const float4*)(w  + rb);
            float4 xf = *(const float4*)(xb + fb);
            float4 wf = *(const float4*)(w  + fb);
            if (low) {
                res.x = -(wr.w * xr.w + wf.x * xf.x);
                res.y = -(wr.z * xr.z + wf.y * xf.y);
                res.z = -(wr.y * xr.y + wf.z * xf.z);
                res.w = -(wr.x * xr.x + wf.w * xf.w);
            } else {
                res.x = wf.x * xf.x - wr.w * xr.w;
                res.y = wf.y * xf.y - wr.z * xr.z;
                res.z = wf.z * xf.z - wr.y * xr.y;
                res.w = wf.w * xf.w - wr.x * xr.x;
            }
        }
        *(float4*)&uf[p] = res;
    }
    __syncthreads();

    // ---- pre-twiddle: z[n] = (u[2n] + i*u[1023-2n]) * (c - i*s) ----
#pragma unroll
    for (int h = 0; h < 2; ++h) {
        int n = tid + h * 256;
        float re = uf[2 * n];
        float im = uf[1023 - 2 * n];
        float a = (float)(4 * n + 1) * (1.0f / 4096.0f);
        float c = cospif(a), s = sinpif(a);
        za[SWZ(n)] = make_float2(re * c + im * s, im * c - re * s);
    }
    __syncthreads();

    // ---- 4 radix-4 Stockham passes (pass j == radix-2 stages 2j, 2j+1) ----
    // pass params: s = 4^j, mh = 256/s; threads [0,128) active.
    // reads  X[t], X[t+128], X[t+256], X[t+384]
    // writes Y[o + r*s], o = t + 3*s*p,  p = t>>(2j), q = t & (s-1)
    // twiddles: w1 = cis(-pi*p/mh), w2 = w1^2, w3 = w1*w2
    float2* X = za;
    float2* Y = zb;
#pragma unroll
    for (int j = 0; j < 4; ++j) {
        const int ls = 2 * j;
        const int s  = 1 << ls;
        const int mh = 256 >> ls;
        if (tid < 128) {
            const int p = tid >> ls;
            float2 P0 = X[SWZ(tid)];
            float2 P1 = X[SWZ(tid + 128)];
            float2 P2 = X[SWZ(tid + 256)];
            float2 P3 = X[SWZ(tid + 384)];
            float ang = (float)p * (1.0f / (float)mh);   // pi units
            float c1 = cospif(ang), s1 = sinpif(ang);
            float c2 = c1 * c1 - s1 * s1, s2 = 2.0f * c1 * s1;
            float c3 = c1 * c2 - s1 * s2, s3 = s1 * c2 + c1 * s2;
            float sax = P0.x + P2.x, say = P0.y + P2.y;
            float sbx = P1.x + P3.x, sby = P1.y + P3.y;
            float dax = P0.x - P2.x, day = P0.y - P2.y;
            float dbx = P1.x - P3.x, dby = P1.y - P3.y;
            const int o = tid + 3 * s * p;
            Y[SWZ(o)] = make_float2(sax + sbx, say + sby);
            float e1x = dax + dby, e1y = day - dbx;           // Da - i*Db
            Y[SWZ(o + s)] = make_float2(e1x * c1 + e1y * s1, e1y * c1 - e1x * s1);
            float e2x = sax - sbx, e2y = say - sby;
            Y[SWZ(o + 2 * s)] = make_float2(e2x * c2 + e2y * s2, e2y * c2 - e2x * s2);
            float e3x = dax - dby, e3y = day + dbx;           // Da + i*Db
            Y[SWZ(o + 3 * s)] = make_float2(e3x * c3 + e3y * s3, e3y * c3 - e3x * s3);
        }
        float2* tmp = X; X = Y; Y = tmp;
        __syncthreads();
    }
    // X now == za (result of pass 3), natural order up to the final stage.

    // ---- final radix-2 stage (twiddle = 1) fused with post-twiddle ----
    // thread tid computes Z[tid] = A + B and Z[tid+256] = A - B in registers.
    {
        float2 A  = X[SWZ(tid)];
        float2 Bv = X[SWZ(tid + 256)];
        float zr[2] = {A.x + Bv.x, A.x - Bv.x};
        float zi[2] = {A.y + Bv.y, A.y - Bv.y};
#pragma unroll
        for (int h = 0; h < 2; ++h) {
            int k = tid + h * 256;
            float a = (float)(4 * k + 1) * (1.0f / 4096.0f);
            float c = cospif(a), s = sinpif(a);
            float re = zr[h] * c + zi[h] * s;            // Re(Z * (c - i*s))
            float im = zi[h] * c - zr[h] * s;            // Im(Z * (c - i*s))
            uf[2 * k]        =  re * 0.04419417382415922f;   // sqrt(2/1024)
            uf[1023 - 2 * k] = -im * 0.04419417382415922f;
        }
    }
    __syncthreads();

    // ---- coalesced store ----
    *(float4*)&out[r * 1024 + tid * 4] = *(const float4*)&uf[tid * 4];
}

// ---------------------------------------------------------------------------
extern "C" void kernel_launch(void* const* d_in, const int* in_sizes, int n_in,
                              void* d_out, int out_size, void* d_ws, size_t ws_size,
                              hipStream_t stream) {
    const float* x = (const float*)d_in[0];   // (8, 1048576) fp32
    const float* w = (const float*)d_in[1];   // (2048,) fp32
    float* out = (float*)d_out;               // (8, 1025, 1024) fp32
    (void)d_ws; (void)ws_size;

    mdct_fft_kernel<<<MROWS, 256, 0, stream>>>(x, w, out);
}

// Round 8
// 92.836 us; speedup vs baseline: 1.3186x; 1.0015x over previous
//
#include <hip/hip_runtime.h>
#include <cmath>

// Problem constants: F=2048, HOP=N=1024, B=8, T=2^20
#define BATCH   8
#define TLEN    1048576
#define NFRM    1025                 // frames per batch row
#define MROWS   (BATCH * NFRM)       // 8200 frames total

// XOR swizzle for FFT ping-pong buffers: every Stockham pass's read AND
// write pattern becomes conflict-free (raw pass0/1 writes were 16-way).
#define SWZ(i) ((i) ^ (((i) >> 4) & 15))

// ---------------------------------------------------------------------------
// Fully-fused MDCT, one 128-thread block (2 waves) per frame.
//   1. fold x (windowed) -> u[1024] fp32 in LDS   (same fold as R1-R7)
//   2. DCT-IV(u) via 512-pt complex FFT:
//        z[n] = (u[2n] + i*u[1023-2n]) * cis(-pi*(4n+1)/4096)
//        Z = FFT_512(z)  — 4 radix-4 Stockham passes (R7-verified network)
//                          + final radix-2 in registers
//        A[k] = Z[k] * cis(-pi*(4k+1)/4096)
//        out[2k] = Re(A)*s, out[1023-2k] = -Im(A)*s, s = sqrt(2/1024)
// R8 changes vs R7:
//   - 128 threads/block: ALL threads active in every phase (R7 idled half
//     the block during the 4 FFT passes); barriers are 2-wave.
//   - uf aliases the zb ping-pong buffer (phases are barrier-disjoint:
//     fold->uf, pretw uf->za, passes za<->zb, final za->uf(=zb), store uf).
//     LDS 12.25 KB -> 8.2 KB -> 16 blocks/CU = 32 waves/CU (full occupancy).
// ---------------------------------------------------------------------------
__global__ __launch_bounds__(128)
void mdct_fft_kernel(const float* __restrict__ x,
                     const float* __restrict__ w,
                     float* __restrict__ out)
{
    __shared__ float2 zz[2][512];       // zz[0]=za; zz[1]=zb, aliased by uf
    float2* const za = zz[0];
    float2* const zb = zz[1];
    float*  const uf = (float*)zz[1];

    const int r   = blockIdx.x;
    const int tid = threadIdx.x;        // [0,128)
    const int b = r / NFRM;
    const int t = r - b * NFRM;

    // ---- fold: y[n] = w[n]*x[(t-1)*1024 + n];
    //   p in [0,512):    u[p] = -( y[1535-p] + y[1536+p] )   (zero iff t==1024)
    //   p in [512,1024): u[p] =    y[p-512]  - y[1535-p]     (zero iff t==0)
    // Each thread does one low-half chunk and one high-half chunk (uniform).
    {
        const float* xb = x + b * TLEN + (t - 1) * 1024;
        // low chunk: p = tid*4
        {
            const int p  = tid * 4;
            float4 res = {0.0f, 0.0f, 0.0f, 0.0f};
            if (t != NFRM - 1) {
                const int rb = 1532 - p;
                const int fb = 1536 + p;
                float4 xr = *(const float4*)(xb + rb);
                float4 wr = *(const float4*)(w  + rb);
                float4 xf = *(const float4*)(xb + fb);
                float4 wf = *(const float4*)(w  + fb);
                res.x = -(wr.w * xr.w + wf.x * xf.x);
                res.y = -(wr.z * xr.z + wf.y * xf.y);
                res.z = -(wr.y * xr.y + wf.z * xf.z);
                res.w = -(wr.x * xr.x + wf.w * xf.w);
            }
            *(float4*)&uf[p] = res;
        }
        // high chunk: p = 512 + tid*4
        {
            const int p  = 512 + tid * 4;
            float4 res = {0.0f, 0.0f, 0.0f, 0.0f};
            if (t != 0) {
                const int rb = 1532 - p;
                const int fb = p - 512;
                float4 xr = *(const float4*)(xb + rb);
                float4 wr = *(const float4*)(w  + rb);
                float4 xf = *(const float4*)(xb + fb);
                float4 wf = *(const float4*)(w  + fb);
                res.x = wf.x * xf.x - wr.w * xr.w;
                res.y = wf.y * xf.y - wr.z * xr.z;
                res.z = wf.z * xf.z - wr.y * xr.y;
                res.w = wf.w * xf.w - wr.x * xr.x;
            }
            *(float4*)&uf[p] = res;
        }
    }
    __syncthreads();

    // ---- pre-twiddle: z[n] = (u[2n] + i*u[1023-2n]) * (c - i*s) ----
#pragma unroll
    for (int h = 0; h < 4; ++h) {
        int n = tid + h * 128;
        float re = uf[2 * n];
        float im = uf[1023 - 2 * n];
        float a = (float)(4 * n + 1) * (1.0f / 4096.0f);
        float c = cospif(a), s = sinpif(a);
        za[SWZ(n)] = make_float2(re * c + im * s, im * c - re * s);
    }
    __syncthreads();

    // ---- 4 radix-4 Stockham passes (identical network to R7, verified) ----
    // pass j: s = 4^j, mh = 256/s, p = tid>>(2j), o = tid + 3*s*p
    // twiddles: w1 = cis(-pi*p/mh), w2 = w1^2, w3 = w1*w2
    float2* X = za;
    float2* Y = zb;
#pragma unroll
    for (int j = 0; j < 4; ++j) {
        const int ls = 2 * j;
        const int s  = 1 << ls;
        const int mh = 256 >> ls;
        const int p = tid >> ls;
        float2 P0 = X[SWZ(tid)];
        float2 P1 = X[SWZ(tid + 128)];
        float2 P2 = X[SWZ(tid + 256)];
        float2 P3 = X[SWZ(tid + 384)];
        float ang = (float)p * (1.0f / (float)mh);   // pi units
        float c1 = cospif(ang), s1 = sinpif(ang);
        float c2 = c1 * c1 - s1 * s1, s2 = 2.0f * c1 * s1;
        float c3 = c1 * c2 - s1 * s2, s3 = s1 * c2 + c1 * s2;
        float sax = P0.x + P2.x, say = P0.y + P2.y;
        float sbx = P1.x + P3.x, sby = P1.y + P3.y;
        float dax = P0.x - P2.x, day = P0.y - P2.y;
        float dbx = P1.x - P3.x, dby = P1.y - P3.y;
        const int o = tid + 3 * s * p;
        Y[SWZ(o)] = make_float2(sax + sbx, say + sby);
        float e1x = dax + dby, e1y = day - dbx;           // Da - i*Db
        Y[SWZ(o + s)] = make_float2(e1x * c1 + e1y * s1, e1y * c1 - e1x * s1);
        float e2x = sax - sbx, e2y = say - sby;
        Y[SWZ(o + 2 * s)] = make_float2(e2x * c2 + e2y * s2, e2y * c2 - e2x * s2);
        float e3x = dax - dby, e3y = day + dbx;           // Da + i*Db
        Y[SWZ(o + 3 * s)] = make_float2(e3x * c3 + e3y * s3, e3y * c3 - e3x * s3);
        float2* tmp = X; X = Y; Y = tmp;
        __syncthreads();
    }
    // after 4 swaps X == za; final stage reads za, writes uf (= zb): no alias
    // hazard (za and zb are distinct regions, phases barrier-separated).

    // ---- final radix-2 (twiddle=1) fused with post-twiddle ----
#pragma unroll
    for (int hh = 0; hh < 2; ++hh) {
        int k0 = tid + hh * 128;                     // [0,256)
        float2 A  = X[SWZ(k0)];
        float2 Bv = X[SWZ(k0 + 256)];
        float zr[2] = {A.x + Bv.x, A.x - Bv.x};      // Z[k0], Z[k0+256]
        float zi[2] = {A.y + Bv.y, A.y - Bv.y};
#pragma unroll
        for (int h = 0; h < 2; ++h) {
            int k = k0 + h * 256;
            float a = (float)(4 * k + 1) * (1.0f / 4096.0f);
            float c = cospif(a), s = sinpif(a);
            float re = zr[h] * c + zi[h] * s;            // Re(Z * (c - i*s))
            float im = zi[h] * c - zr[h] * s;            // Im(Z * (c - i*s))
            uf[2 * k]        =  re * 0.04419417382415922f;   // sqrt(2/1024)
            uf[1023 - 2 * k] = -im * 0.04419417382415922f;
        }
    }
    __syncthreads();

    // ---- coalesced store: two float4 per thread ----
    *(float4*)&out[r * 1024 + tid * 4]       = *(const float4*)&uf[tid * 4];
    *(float4*)&out[r * 1024 + 512 + tid * 4] = *(const float4*)&uf[512 + tid * 4];
}

// ---------------------------------------------------------------------------
extern "C" void kernel_launch(void* const* d_in, const int* in_sizes, int n_in,
                              void* d_out, int out_size, void* d_ws, size_t ws_size,
                              hipStream_t stream) {
    const float* x = (const float*)d_in[0];   // (8, 1048576) fp32
    const float* w = (const float*)d_in[1];   // (2048,) fp32
    float* out = (float*)d_out;               // (8, 1025, 1024) fp32
    (void)d_ws; (void)ws_size;

    mdct_fft_kernel<<<MROWS, 128, 0, stream>>>(x, w, out);
}